// Round 1
// baseline (479.990 us; speedup 1.0000x reference)
//
#include <hip/hip_runtime.h>
#include <stdint.h>

#define B_ 16
#define C_ 64
#define H_ 112
#define W_ 112
#define N_ 256

typedef __attribute__((ext_vector_type(8))) short short8;
typedef __attribute__((ext_vector_type(4))) float floatx4;

__device__ __forceinline__ uint32_t f2bf_bits(float f) {
  uint32_t u = __float_as_uint(f);
  return (u + 0x7fffu + ((u >> 16) & 1u)) >> 16;  // RNE f32 -> bf16 bits
}

// NCHW f32 -> [b][i][j][c] packed uint32: low16 = bf16(x), high16 = bf16(x^2)
__global__ __launch_bounds__(256) void xform_x(const float* __restrict__ x,
                                               uint32_t* __restrict__ xq) {
  __shared__ float ls[64][113];  // +1 pad breaks bank conflicts on transpose read
  int bi = blockIdx.x;
  int b = bi / H_, i = bi % H_;
  const float* xbase = x + ((size_t)b * C_) * (H_ * W_) + (size_t)i * W_;
  for (int idx = threadIdx.x; idx < C_ * W_; idx += 256) {
    int c = idx / W_, j = idx - c * W_;
    ls[c][j] = xbase[(size_t)c * (H_ * W_) + j];
  }
  __syncthreads();
  uint32_t* orow = xq + ((size_t)(b * H_ + i)) * (W_ * C_);
  for (int idx = threadIdx.x; idx < W_ * C_; idx += 256) {
    int j = idx >> 6, c = idx & 63;
    float v = ls[c][j];
    float v2 = v * v;
    orow[idx] = f2bf_bits(v) | (f2bf_bits(v2) << 16);
  }
}

// Weights -> Wg[cg(2)][tap(9)][n(256)][ci(32)] uint32 pairs:
//   low16 = bf16(2*|w|*t)  (multiplies x),  high16 = bf16(-|w|)  (multiplies x^2)
__global__ __launch_bounds__(256) void prep_w(const float* __restrict__ sw,
                                              const float* __restrict__ tp,
                                              uint32_t* __restrict__ Wg) {
  int idx = blockIdx.x * 256 + threadIdx.x;  // 0 .. 16383
  if (idx >= N_ * C_) return;
  int n = idx >> 6, c = idx & 63;
  int cg = c >> 5, ci = c & 31;
  const float* swp = sw + (size_t)(n * C_ + c) * 9;
  const float* tpp = tp + (size_t)(n * C_ + c) * 9;
#pragma unroll
  for (int tap = 0; tap < 9; ++tap) {
    float w = fabsf(swp[tap]);
    float t = tpp[tap];
    uint32_t v = f2bf_bits(2.0f * w * t) | (f2bf_bits(-w) << 16);
    Wg[((size_t)(cg * 9 + tap) * N_ + n) * 32 + ci] = v;
  }
}

// const[n] = sum |w| t^2  (fp32 exact-ish)
__global__ __launch_bounds__(64) void prep_c(const float* __restrict__ sw,
                                             const float* __restrict__ tp,
                                             float* __restrict__ cN) {
  int n = blockIdx.x, c = threadIdx.x;
  const float* swp = sw + (size_t)(n * C_ + c) * 9;
  const float* tpp = tp + (size_t)(n * C_ + c) * 9;
  float s = 0.f;
#pragma unroll
  for (int tap = 0; tap < 9; ++tap) s += fabsf(swp[tap]) * tpp[tap] * tpp[tap];
#pragma unroll
  for (int off = 32; off > 0; off >>= 1) s += __shfl_down(s, off);
  if (c == 0) cN[n] = s;
}

// Output tile: 128 n x 128 pixels (8 rows x 16 cols). 4 waves, each 64n x 64pix.
// K-loop: cg(2 channel groups of 32) x tap(9) x kk(2 MFMA K-steps of 32 bf16-k).
__global__ __launch_bounds__(256) void sim_main(const uint32_t* __restrict__ xq,
                                                const uint32_t* __restrict__ Wg,
                                                const float* __restrict__ cN,
                                                float* __restrict__ out) {
  __shared__ uint32_t xs[10 * 18 * 36];  // halo tile, site stride 36 dw (16B-aligned, 2-way banks)
  __shared__ uint32_t bs[128 * 36];      // weight tile, row stride 36 dw

  int bx = blockIdx.x;
  int nb = bx & 1;
  bx >>= 1;
  int b = bx / 98;
  int rem = bx - b * 98;
  int rt = rem / 7, ct = rem - rt * 7;
  int r0 = rt * 8, c0 = ct * 16;
  int tid = threadIdx.x;
  int lane = tid & 63, wv = tid >> 6;
  int wn = wv & 1, wp = wv >> 1;
  int l15 = lane & 15, l4 = lane >> 4;

  floatx4 acc[4][4];  // [nt][pt]; D row = n (l4*4+reg), D col = pixel (l15)
#pragma unroll
  for (int a = 0; a < 4; ++a)
#pragma unroll
    for (int p = 0; p < 4; ++p) acc[a][p] = (floatx4){0.f, 0.f, 0.f, 0.f};

  const uint32_t* xim = xq + (size_t)b * (H_ * W_ * C_);

  for (int cg = 0; cg < 2; ++cg) {
    if (cg) __syncthreads();  // prior cg's readers done before xs overwrite
    // stage 10x18 halo sites, 32 channels (128B) each, zero-filled out of bounds
    for (int idx = tid; idx < 180 * 8; idx += 256) {
      int s = idx >> 3, ch = idx & 7;
      int row = s / 18, col = s - row * 18;
      int gi = r0 - 1 + row, gj = c0 - 1 + col;
      uint4 v = make_uint4(0u, 0u, 0u, 0u);
      if (gi >= 0 && gi < H_ && gj >= 0 && gj < W_)
        v = *(const uint4*)(xim + ((size_t)(gi * W_ + gj)) * C_ + cg * 32 + ch * 4);
      *(uint4*)(&xs[s * 36 + ch * 4]) = v;
    }
    for (int tap = 0; tap < 9; ++tap) {
      __syncthreads();  // prev tap's bs readers done (first iter: also orders xs)
      const uint32_t* wsrc = Wg + ((size_t)((cg * 9 + tap) * N_ + nb * 128)) * 32;
      for (int idx = tid; idx < 128 * 8; idx += 256) {
        int n = idx >> 3, ch = idx & 7;
        *(uint4*)(&bs[n * 36 + ch * 4]) = *(const uint4*)(wsrc + n * 32 + ch * 4);
      }
      __syncthreads();
      int dp = tap / 3, dq = tap - dp * 3;
#pragma unroll
      for (int kk = 0; kk < 2; ++kk) {
        short8 af[4], bfr[4];
#pragma unroll
        for (int nt = 0; nt < 4; ++nt)
          af[nt] = *(const short8*)(&bs[(wn * 64 + nt * 16 + l15) * 36 + kk * 16 + l4 * 4]);
#pragma unroll
        for (int pt = 0; pt < 4; ++pt) {
          int hrow = wp * 4 + pt + dp;
          int hcol = l15 + dq;
          bfr[pt] = *(const short8*)(&xs[(hrow * 18 + hcol) * 36 + kk * 16 + l4 * 4]);
        }
#pragma unroll
        for (int nt = 0; nt < 4; ++nt)
#pragma unroll
          for (int pt = 0; pt < 4; ++pt)
            acc[nt][pt] =
                __builtin_amdgcn_mfma_f32_16x16x32_bf16(af[nt], bfr[pt], acc[nt][pt], 0, 0, 0);
      }
    }
  }

  // epilogue: out[b][n][r][col] = acc - const[n]; lanes 0..15 -> consecutive cols
#pragma unroll
  for (int nt = 0; nt < 4; ++nt) {
#pragma unroll
    for (int v = 0; v < 4; ++v) {
      int n = nb * 128 + wn * 64 + nt * 16 + l4 * 4 + v;
      float cv = cN[n];
#pragma unroll
      for (int pt = 0; pt < 4; ++pt) {
        int r = r0 + wp * 4 + pt;
        int col = c0 + l15;
        out[(((size_t)b * N_ + n) * H_ + r) * W_ + col] = acc[nt][pt][v] - cv;
      }
    }
  }
}

extern "C" void kernel_launch(void* const* d_in, const int* in_sizes, int n_in,
                              void* d_out, int out_size, void* d_ws, size_t ws_size,
                              hipStream_t stream) {
  const float* x = (const float*)d_in[0];
  const float* sw = (const float*)d_in[1];
  const float* tp = (const float*)d_in[2];
  float* out = (float*)d_out;

  // workspace layout
  const size_t xq_bytes = (size_t)B_ * H_ * W_ * C_ * 4;  // 51,380,224
  const size_t wg_bytes = (size_t)2 * 9 * N_ * 32 * 4;    // 589,824
  uint32_t* xq = (uint32_t*)d_ws;
  uint32_t* Wg = (uint32_t*)((char*)d_ws + xq_bytes);
  float* cN = (float*)((char*)d_ws + xq_bytes + wg_bytes);

  xform_x<<<dim3(B_ * H_), dim3(256), 0, stream>>>(x, xq);
  prep_w<<<dim3((N_ * C_ + 255) / 256), dim3(256), 0, stream>>>(sw, tp, Wg);
  prep_c<<<dim3(N_), dim3(64), 0, stream>>>(sw, tp, cN);
  sim_main<<<dim3(2 * B_ * 14 * 7), dim3(256), 0, stream>>>(xq, Wg, cN, out);
}

// Round 3
// 395.199 us; speedup vs baseline: 1.2146x; 1.2146x over previous
//
#include <hip/hip_runtime.h>
#include <stdint.h>

#define B_ 16
#define C_ 64
#define H_ 112
#define W_ 112
#define N_ 256

typedef __attribute__((ext_vector_type(8))) short short8;
typedef __attribute__((ext_vector_type(4))) float floatx4;

__device__ __forceinline__ uint32_t f2bf_bits(float f) {
  uint32_t u = __float_as_uint(f);
  return (u + 0x7fffu + ((u >> 16) & 1u)) >> 16;  // RNE f32 -> bf16 bits
}

// NCHW f32 -> [b][i][j][c] packed uint32: low16 = bf16(x), high16 = bf16(x^2)
__global__ __launch_bounds__(256) void xform_x(const float* __restrict__ x,
                                               uint32_t* __restrict__ xq) {
  __shared__ float ls[64][113];  // +1 pad: odd stride -> conflict-free transpose read
  int bi = blockIdx.x;
  int b = bi / H_, i = bi % H_;
  const float* xbase = x + ((size_t)b * C_) * (H_ * W_) + (size_t)i * W_;
  for (int idx = threadIdx.x; idx < C_ * W_; idx += 256) {
    int c = idx / W_, j = idx - c * W_;
    ls[c][j] = xbase[(size_t)c * (H_ * W_) + j];
  }
  __syncthreads();
  uint32_t* orow = xq + ((size_t)(b * H_ + i)) * (W_ * C_);
  for (int idx = threadIdx.x; idx < W_ * C_; idx += 256) {
    int j = idx >> 6, c = idx & 63;
    float v = ls[c][j];
    float v2 = v * v;
    orow[idx] = f2bf_bits(v) | (f2bf_bits(v2) << 16);
  }
}

// Weights -> Wg[cg(2)][tap(9)][kk(2)][n(256)][pos(16)] uint32 pairs:
//   low16 = bf16(2*|w|*t) (multiplies x), high16 = bf16(-|w|) (multiplies x^2)
// Layout makes one wave's A-fragment load ((n..n+15) x 64B) fully contiguous (1KB).
// Also computes cN[n] = sum |w| t^2 (fused, one block per n).
__global__ __launch_bounds__(64) void prep_wc(const float* __restrict__ sw,
                                              const float* __restrict__ tp,
                                              uint32_t* __restrict__ Wg,
                                              float* __restrict__ cN) {
  int n = blockIdx.x, c = threadIdx.x;  // c = 0..63
  int cg = c >> 5, ci = c & 31;
  int kk = ci >> 4, pos = ci & 15;
  const float* swp = sw + (size_t)(n * C_ + c) * 9;
  const float* tpp = tp + (size_t)(n * C_ + c) * 9;
  float s = 0.f;
#pragma unroll
  for (int tap = 0; tap < 9; ++tap) {
    float w = fabsf(swp[tap]);
    float t = tpp[tap];
    s += w * t * t;
    uint32_t v = f2bf_bits(2.0f * w * t) | (f2bf_bits(-w) << 16);
    Wg[(size_t)(((cg * 9 + tap) * 2 + kk) * (N_ * 16)) + n * 16 + pos] = v;
  }
#pragma unroll
  for (int off = 32; off > 0; off >>= 1) s += __shfl_down(s, off);
  if (c == 0) cN[n] = s;
}

// Output tile: 128 n x 128 pixels (8 rows x 16 cols). 4 waves, each 64n x 64pix.
// Weights (L2-resident, 576KB) loaded straight to A-fragments via global dwordx4
// -> no weight LDS, only 3 barriers per block (vs 37 in v1).
__global__ __launch_bounds__(256, 4) void sim_main(const uint32_t* __restrict__ xq,
                                                   const uint32_t* __restrict__ Wg,
                                                   const float* __restrict__ cN,
                                                   float* __restrict__ out) {
  __shared__ uint32_t xs[10 * 18 * 36];  // halo tile, site stride 36 dw (16B-aligned)

  int bx = blockIdx.x;
  int nb = bx & 1;
  bx >>= 1;
  int b = bx / 98;
  int rem = bx - b * 98;
  int rt = rem / 7, ct = rem - rt * 7;
  int r0 = rt * 8, c0 = ct * 16;
  int tid = threadIdx.x;
  int lane = tid & 63, wv = tid >> 6;
  int wn = wv & 1, wp = wv >> 1;
  int l15 = lane & 15, l4 = lane >> 4;

  floatx4 acc[4][4];  // [nt][pt]; D row = n (l4*4+reg), D col = pixel (l15)
#pragma unroll
  for (int a = 0; a < 4; ++a)
#pragma unroll
    for (int p = 0; p < 4; ++p) acc[a][p] = (floatx4){0.f, 0.f, 0.f, 0.f};

  const uint32_t* xim = xq + (size_t)b * (H_ * W_ * C_);
  // per-lane A-fragment base (row n = nb*128+wn*64+l15, dwords l4*4..l4*4+3)
  const uint32_t* wlane = Wg + (nb * 128 + wn * 64 + l15) * 16 + l4 * 4;

  for (int cg = 0; cg < 2; ++cg) {
    if (cg) __syncthreads();  // prior cg's xs readers done before overwrite
    // stage 10x18 halo sites, 32 channels (128B) each, zero-filled out of bounds
    for (int idx = tid; idx < 180 * 8; idx += 256) {
      int s = idx >> 3, ch = idx & 7;
      int row = s / 18, col = s - row * 18;
      int gi = r0 - 1 + row, gj = c0 - 1 + col;
      uint4 v = make_uint4(0u, 0u, 0u, 0u);
      if ((unsigned)gi < (unsigned)H_ && (unsigned)gj < (unsigned)W_)
        v = *(const uint4*)(xim + ((size_t)(gi * W_ + gj)) * C_ + cg * 32 + ch * 4);
      *(uint4*)(&xs[s * 36 + ch * 4]) = v;
    }
    __syncthreads();

#pragma unroll 1
    for (int tap = 0; tap < 9; ++tap) {
      int dp = tap / 3, dq = tap - dp * 3;
      const uint32_t* wp0 = wlane + (size_t)((cg * 9 + tap) * 2) * (N_ * 16);
#pragma unroll
      for (int kk = 0; kk < 2; ++kk) {  // only 8 frags live at a time (32 VGPRs)
        short8 af[4], bfr[4];
#pragma unroll
        for (int nt = 0; nt < 4; ++nt)
          af[nt] = *(const short8*)(wp0 + (size_t)kk * (N_ * 16) + nt * 16 * 16);
#pragma unroll
        for (int pt = 0; pt < 4; ++pt)
          bfr[pt] =
              *(const short8*)(&xs[((wp * 4 + pt + dp) * 18 + l15 + dq) * 36 + kk * 16 + l4 * 4]);
#pragma unroll
        for (int nt = 0; nt < 4; ++nt)
#pragma unroll
          for (int pt = 0; pt < 4; ++pt)
            acc[nt][pt] =
                __builtin_amdgcn_mfma_f32_16x16x32_bf16(af[nt], bfr[pt], acc[nt][pt], 0, 0, 0);
      }
    }
  }

  // epilogue: out[b][n][r][col] = acc - const[n]; lanes 0..15 -> consecutive cols
#pragma unroll
  for (int nt = 0; nt < 4; ++nt) {
#pragma unroll
    for (int v = 0; v < 4; ++v) {
      int n = nb * 128 + wn * 64 + nt * 16 + l4 * 4 + v;
      float cv = cN[n];
#pragma unroll
      for (int pt = 0; pt < 4; ++pt) {
        int r = r0 + wp * 4 + pt;
        int col = c0 + l15;
        out[(((size_t)b * N_ + n) * H_ + r) * W_ + col] = acc[nt][pt][v] - cv;
      }
    }
  }
}

extern "C" void kernel_launch(void* const* d_in, const int* in_sizes, int n_in,
                              void* d_out, int out_size, void* d_ws, size_t ws_size,
                              hipStream_t stream) {
  const float* x = (const float*)d_in[0];
  const float* sw = (const float*)d_in[1];
  const float* tp = (const float*)d_in[2];
  float* out = (float*)d_out;

  // workspace layout
  const size_t xq_bytes = (size_t)B_ * H_ * W_ * C_ * 4;    // 51,380,224
  const size_t wg_bytes = (size_t)2 * 9 * 2 * N_ * 16 * 4;  // 589,824
  uint32_t* xq = (uint32_t*)d_ws;
  uint32_t* Wg = (uint32_t*)((char*)d_ws + xq_bytes);
  float* cN = (float*)((char*)d_ws + xq_bytes + wg_bytes);

  xform_x<<<dim3(B_ * H_), dim3(256), 0, stream>>>(x, xq);
  prep_wc<<<dim3(N_), dim3(64), 0, stream>>>(sw, tp, Wg, cN);
  sim_main<<<dim3(2 * B_ * 14 * 7), dim3(256), 0, stream>>>(xq, Wg, cN, out);
}